// Round 2
// baseline (701.611 us; speedup 1.0000x reference)
//
#include <hip/hip_runtime.h>
#include <math.h>

#define EPSF 1e-8f

// acc layout in d_ws (doubles), padded to separate 128B cache lines:
//   acc[0]  = sum min_scale
//   acc[16] = sum variance terms
//   acc[32] = sum (1 - |axis.n|)
#define ACC_MIN 0
#define ACC_VAR 16
#define ACC_NRM 32

__global__ __launch_bounds__(256) void align_main(
    const float* __restrict__ xyz,
    const float* __restrict__ scales,
    const float* __restrict__ rotation,
    const int*   __restrict__ knn,
    const float* __restrict__ normal,
    double* __restrict__ acc,
    int n)
{
    float s_min = 0.f;   // Σ min_scale
    float s_var = 0.f;   // Σ_i Σ_k (d - mean_d)^2
    float s_nrm = 0.f;   // Σ (1 - |axis·n̂|)

    const int stride = gridDim.x * blockDim.x;
    for (int i = blockIdx.x * blockDim.x + threadIdx.x; i < n; i += stride) {
        // ---- point + normal ----
        const float px = xyz[3*(size_t)i+0], py = xyz[3*(size_t)i+1], pz = xyz[3*(size_t)i+2];
        float nx = normal[3*(size_t)i+0], ny = normal[3*(size_t)i+1], nz = normal[3*(size_t)i+2];
        const float ninv = 1.f / (sqrtf(nx*nx + ny*ny + nz*nz) + EPSF);
        nx *= ninv; ny *= ninv; nz *= ninv;

        // ---- scales: min + argmin (first-min semantics) ----
        const float s0 = scales[3*(size_t)i+0], s1 = scales[3*(size_t)i+1], s2 = scales[3*(size_t)i+2];
        s_min += fminf(s0, fminf(s1, s2));
        const int min_idx = (s0 <= s1 && s0 <= s2) ? 0 : ((s1 <= s2) ? 1 : 2);

        // ---- knn gather: d_k = (nbr - p)·n̂ ; variance via Σd² - (Σd)²/K ----
        const int4* krow = (const int4*)(knn + (size_t)16 * i);
        float sum_d = 0.f, sum_d2 = 0.f;
        #pragma unroll
        for (int q = 0; q < 4; ++q) {
            const int4 j4 = krow[q];
            const int js[4] = { j4.x, j4.y, j4.z, j4.w };
            #pragma unroll
            for (int t = 0; t < 4; ++t) {
                const size_t j = (size_t)js[t] * 3;
                const float dx = xyz[j+0] - px;
                const float dy = xyz[j+1] - py;
                const float dz = xyz[j+2] - pz;
                const float d = dx*nx + dy*ny + dz*nz;
                sum_d  += d;
                sum_d2 += d*d;
            }
        }
        s_var += sum_d2 - sum_d * sum_d * (1.f/16.f);

        // ---- quaternion -> rotmat column(min_idx) ----
        const float4 q = *(const float4*)(rotation + (size_t)4 * i);
        const float qw = q.x, qx = q.y, qy = q.z, qz = q.w;
        const float qinv = 1.f / (sqrtf(qw*qw + qx*qx + qy*qy + qz*qz) + EPSF);
        const float w = qw*qinv, x = qx*qinv, y = qy*qinv, z = qz*qinv;
        float ax, ay, az;
        if (min_idx == 0) {
            ax = 1.f - 2.f*(y*y + z*z); ay = 2.f*(x*y + w*z); az = 2.f*(x*z - w*y);
        } else if (min_idx == 1) {
            ax = 2.f*(x*y - w*z); ay = 1.f - 2.f*(x*x + z*z); az = 2.f*(y*z + w*x);
        } else {
            ax = 2.f*(x*z + w*y); ay = 2.f*(y*z - w*x); az = 1.f - 2.f*(x*x + y*y);
        }
        s_nrm += 1.f - fabsf(ax*nx + ay*ny + az*nz);
    }

    // ---- wave64 shuffle reduction ----
    #pragma unroll
    for (int off = 32; off > 0; off >>= 1) {
        s_min += __shfl_down(s_min, off);
        s_var += __shfl_down(s_var, off);
        s_nrm += __shfl_down(s_nrm, off);
    }

    __shared__ float red[3][4];
    const int lane = threadIdx.x & 63;
    const int wave = threadIdx.x >> 6;
    if (lane == 0) { red[0][wave] = s_min; red[1][wave] = s_var; red[2][wave] = s_nrm; }
    __syncthreads();
    if (threadIdx.x == 0) {
        double a = 0, b = 0, c = 0;
        #pragma unroll
        for (int wv = 0; wv < 4; ++wv) { a += red[0][wv]; b += red[1][wv]; c += red[2][wv]; }
        atomicAdd(&acc[ACC_MIN], a);
        atomicAdd(&acc[ACC_VAR], b);
        atomicAdd(&acc[ACC_NRM], c);
    }
}

__global__ void align_finalize(const double* __restrict__ acc,
                               float* __restrict__ out, int n)
{
    if (threadIdx.x == 0) {
        out[0] = (float)(acc[ACC_MIN] / (double)n);
        out[1] = (float)(acc[ACC_VAR] / ((double)n * 16.0));
        out[2] = (float)(acc[ACC_NRM] / (double)n);
    }
}

extern "C" void kernel_launch(void* const* d_in, const int* in_sizes, int n_in,
                              void* d_out, int out_size, void* d_ws, size_t ws_size,
                              hipStream_t stream) {
    const float* xyz      = (const float*)d_in[0];
    const float* scales   = (const float*)d_in[2];
    const float* rotation = (const float*)d_in[3];
    const int*   knn      = (const int*)d_in[4];
    const float* normal   = (const float*)d_in[5];
    float* out = (float*)d_out;
    double* acc = (double*)d_ws;

    const int n = in_sizes[1];  // xyz_id count == N

    hipMemsetAsync(acc, 0, 33 * sizeof(double), stream);

    const int block = 256;
    int grid = (n + block - 1) / block;
    if (grid > 2048) grid = 2048;
    align_main<<<grid, block, 0, stream>>>(xyz, scales, rotation, knn, normal, acc, n);
    align_finalize<<<1, 64, 0, stream>>>(acc, out, n);
}